// Round 11
// baseline (275.385 us; speedup 1.0000x reference)
//
#include <hip/hip_runtime.h>
#include <hip/hip_bf16.h>

// Attention_82841329205539: B=2, N=2048, C=768, H=12, D=64, window=129
// Inputs fp32 (dict order), OUTPUT fp32 [B,N,C].
// r6:1485 r7:809 r8:444 r10:270 us. r10 lesson: scattered 2B epilogue stores
// -> 8.5x HBM write amplification (WRITE_SIZE 160MB vs 19MB ideal).
#define Bsz   2
#define Nseq  2048
#define Cdim  768
#define E3    2304     // 3*C
#define Hh    12
#define Dd    64
#define HALF  64
#define SCALEF 0.125f

typedef __attribute__((ext_vector_type(8))) short short8;
typedef __attribute__((ext_vector_type(4))) float f32x4;

__device__ __forceinline__ unsigned short f2bf(float f) {
    unsigned int u = __float_as_uint(f);
    u = (u + 0x7FFFu + ((u >> 16) & 1u)) >> 16;
    return (unsigned short)u;
}
__device__ __forceinline__ float lo2f(unsigned int u) { return __uint_as_float(u << 16); }
__device__ __forceinline__ float hi2f(unsigned int u) { return __uint_as_float(u & 0xffff0000u); }

// ---------------------------------------------------------------------------
__global__ __launch_bounds__(256) void f32_to_bf16(
    const float* __restrict__ src, unsigned short* __restrict__ dst, int n)
{
    const int i = (blockIdx.x * 256 + threadIdx.x) * 4;
    if (i < n) {
        float4 v = *(const float4*)&src[i];
        union { unsigned short us[4]; uint2 u2; } pk;
        pk.us[0] = f2bf(v.x); pk.us[1] = f2bf(v.y);
        pk.us[2] = f2bf(v.z); pk.us[3] = f2bf(v.w);
        *(uint2*)&dst[i] = pk.u2;
    }
}

// ---------------------------------------------------------------------------
// MFMA GEMM: 128x128 tile, 4 waves (2x2 of 64x64), 4x4 MFMA 16x16x32 bf16.
// A[M][768], W[N][768] bf16 row-major; out[m][n] = sum_k A[m][k]*W[n][k].
// Frag layouts (m89/m91 verified): A/B elem j = M[row=lane&15][k=quad*8+j];
// C/D: m=quad*4+reg, n=lane&15.
// ---------------------------------------------------------------------------
#define BK  64
#define AST 72     // staging LDS row stride (shorts)
#define CST 136    // epilogue C-tile row stride (shorts), 272 B, 16B-aligned

// ---------------------------------------------------------------------------
// Kernel: QKV projection -> bf16 qkv[bn][2304] ROW-MAJOR (no head scatter;
// swin does the head addressing). grid (18, 32).
// ---------------------------------------------------------------------------
__global__ __launch_bounds__(256) void qkv_mfma(
    const unsigned short* __restrict__ Ab, const unsigned short* __restrict__ Wb,
    unsigned short* __restrict__ qkvb)
{
    __shared__ __align__(16) unsigned short smem[2 * 128 * AST];  // 36864 B
    unsigned short (*Al)[AST] = (unsigned short(*)[AST])smem;
    unsigned short (*Bl)[AST] = (unsigned short(*)[AST])(smem + 128 * AST);

    const int t    = threadIdx.x;
    const int row0 = blockIdx.y * 128;
    const int col0 = blockIdx.x * 128;
    const int lane = t & 63, wave = t >> 6;
    const int wm = wave >> 1, wn = wave & 1;
    const int ln = lane & 15, quad = lane >> 4;

    f32x4 acc[4][4] = {};

    for (int k0 = 0; k0 < Cdim; k0 += BK) {
        uint4 ra[4], rb[4];
#pragma unroll
        for (int j = 0; j < 4; ++j) {
            const int F = t + j * 256, r = F >> 3, c = F & 7;
            ra[j] = *(const uint4*)&Ab[(size_t)(row0 + r) * Cdim + k0 + c * 8];
            rb[j] = *(const uint4*)&Wb[(size_t)(col0 + r) * Cdim + k0 + c * 8];
        }
        __syncthreads();
#pragma unroll
        for (int j = 0; j < 4; ++j) {
            const int F = t + j * 256, r = F >> 3, c = F & 7;
            *(uint4*)&Al[r][c * 8] = ra[j];
            *(uint4*)&Bl[r][c * 8] = rb[j];
        }
        __syncthreads();
#pragma unroll
        for (int kk = 0; kk < BK; kk += 32) {
            short8 af[4], bf[4];
#pragma unroll
            for (int mi = 0; mi < 4; ++mi)
                af[mi] = *(const short8*)&Al[wm*64 + mi*16 + ln][kk + quad*8];
#pragma unroll
            for (int ni = 0; ni < 4; ++ni)
                bf[ni] = *(const short8*)&Bl[wn*64 + ni*16 + ln][kk + quad*8];
#pragma unroll
            for (int mi = 0; mi < 4; ++mi)
#pragma unroll
                for (int ni = 0; ni < 4; ++ni)
                    acc[mi][ni] = __builtin_amdgcn_mfma_f32_16x16x32_bf16(
                        af[mi], bf[ni], acc[mi][ni], 0, 0, 0);
        }
    }

    // Epilogue: acc -> LDS bf16 tile -> coalesced uint4 row stores.
    __syncthreads();
    unsigned short (*Cs)[CST] = (unsigned short(*)[CST])smem;   // 34816 B
#pragma unroll
    for (int mi = 0; mi < 4; ++mi)
#pragma unroll
        for (int ni = 0; ni < 4; ++ni)
#pragma unroll
            for (int reg = 0; reg < 4; ++reg)
                Cs[wm*64 + mi*16 + quad*4 + reg][wn*64 + ni*16 + ln] =
                    f2bf(acc[mi][ni][reg]);
    __syncthreads();
    for (int idx = t; idx < 128 * 16; idx += 256) {
        const int r = idx >> 4, c8 = idx & 15;
        *(uint4*)&qkvb[(size_t)(row0 + r) * E3 + col0 + c8 * 8] =
            *(const uint4*)&Cs[r][c8 * 8];
    }
}

// ---------------------------------------------------------------------------
// Kernel: output projection + bias -> fp32 out. grid (6, 32).
// Same core; epilogue in two 64-col passes (fp32 tile > LDS budget).
// ---------------------------------------------------------------------------
__global__ __launch_bounds__(256) void proj_mfma(
    const unsigned short* __restrict__ Ab, const unsigned short* __restrict__ Wb,
    const float* __restrict__ bias, float* __restrict__ out)
{
    __shared__ __align__(16) unsigned short smem[2 * 128 * AST];
    unsigned short (*Al)[AST] = (unsigned short(*)[AST])smem;
    unsigned short (*Bl)[AST] = (unsigned short(*)[AST])(smem + 128 * AST);

    const int t    = threadIdx.x;
    const int row0 = blockIdx.y * 128;
    const int col0 = blockIdx.x * 128;
    const int lane = t & 63, wave = t >> 6;
    const int wm = wave >> 1, wn = wave & 1;
    const int ln = lane & 15, quad = lane >> 4;

    f32x4 acc[4][4] = {};

    for (int k0 = 0; k0 < Cdim; k0 += BK) {
        uint4 ra[4], rb[4];
#pragma unroll
        for (int j = 0; j < 4; ++j) {
            const int F = t + j * 256, r = F >> 3, c = F & 7;
            ra[j] = *(const uint4*)&Ab[(size_t)(row0 + r) * Cdim + k0 + c * 8];
            rb[j] = *(const uint4*)&Wb[(size_t)(col0 + r) * Cdim + k0 + c * 8];
        }
        __syncthreads();
#pragma unroll
        for (int j = 0; j < 4; ++j) {
            const int F = t + j * 256, r = F >> 3, c = F & 7;
            *(uint4*)&Al[r][c * 8] = ra[j];
            *(uint4*)&Bl[r][c * 8] = rb[j];
        }
        __syncthreads();
#pragma unroll
        for (int kk = 0; kk < BK; kk += 32) {
            short8 af[4], bf[4];
#pragma unroll
            for (int mi = 0; mi < 4; ++mi)
                af[mi] = *(const short8*)&Al[wm*64 + mi*16 + ln][kk + quad*8];
#pragma unroll
            for (int ni = 0; ni < 4; ++ni)
                bf[ni] = *(const short8*)&Bl[wn*64 + ni*16 + ln][kk + quad*8];
#pragma unroll
            for (int mi = 0; mi < 4; ++mi)
#pragma unroll
                for (int ni = 0; ni < 4; ++ni)
                    acc[mi][ni] = __builtin_amdgcn_mfma_f32_16x16x32_bf16(
                        af[mi], bf[ni], acc[mi][ni], 0, 0, 0);
        }
    }

    float (*Csf)[68] = (float(*)[68])smem;   // 128 x 68 fp32 = 34816 B
#pragma unroll
    for (int p = 0; p < 2; ++p) {
        __syncthreads();
        if (wn == p)
#pragma unroll
            for (int mi = 0; mi < 4; ++mi)
#pragma unroll
                for (int ni = 0; ni < 4; ++ni)
#pragma unroll
                    for (int reg = 0; reg < 4; ++reg)
                        Csf[wm*64 + mi*16 + quad*4 + reg][ni*16 + ln] =
                            acc[mi][ni][reg];
        __syncthreads();
        for (int idx = t; idx < 128 * 16; idx += 256) {
            const int r = idx >> 4, c4 = idx & 15;
            const int col = col0 + p * 64 + c4 * 4;
            float4 v  = *(const float4*)&Csf[r][c4 * 4];
            float4 bv = *(const float4*)&bias[col];
            *(float4*)&out[(size_t)(row0 + r) * Cdim + col] =
                make_float4(v.x + bv.x, v.y + bv.y, v.z + bv.z, v.w + bv.w);
        }
    }
}

// ---------------------------------------------------------------------------
// Kernel: tiled sliding-window attention, reading ROW-MAJOR qkv[bn][2304].
// 32 q/block, 160-row K/V window in LDS bf16, 8 lanes/query. grid (64, 24).
// ---------------------------------------------------------------------------
#define TQ   32
#define ROWS 160
#define KST  72
#define SST  168

__global__ __launch_bounds__(256) void swin_attn(
    const unsigned short* __restrict__ qkvb, unsigned short* __restrict__ ab)
{
    __shared__ __align__(16) unsigned short Qs[TQ][KST];
    __shared__ __align__(16) unsigned short Ks[ROWS][KST];
    __shared__ __align__(16) unsigned short Vs[ROWS][KST];
    __shared__ __align__(16) unsigned short sc[TQ][SST];

    const int t  = threadIdx.x;
    const int bh = blockIdx.y;
    const int b  = bh / Hh, h = bh % Hh;
    const int i0 = blockIdx.x * TQ;
    const int hoff = h * Dd;     // column offset of this head within C

    // stage Q(32) + K(160) + V(160) head-rows from row-major qkv; OOB -> 0
    for (int F = t; F < 352 * 8; F += 256) {
        const int r = F >> 3, c8 = F & 7;
        const unsigned short* base = nullptr;
        unsigned short* dst;
        if (r < 32) {
            base = qkvb + (size_t)(b * Nseq + (i0 + r)) * E3 + hoff;   // Q sec
            dst = &Qs[r][c8 * 8];
        } else if (r < 192) {
            const int g = i0 - HALF + (r - 32);
            if (g >= 0 && g < Nseq)
                base = qkvb + (size_t)(b * Nseq + g) * E3 + Cdim + hoff;  // K
            dst = &Ks[r - 32][c8 * 8];
        } else {
            const int g = i0 - HALF + (r - 192);
            if (g >= 0 && g < Nseq)
                base = qkvb + (size_t)(b * Nseq + g) * E3 + 2 * Cdim + hoff; // V
            dst = &Vs[r - 192][c8 * 8];
        }
        uint4 v = make_uint4(0u, 0u, 0u, 0u);
        if (base) v = *(const uint4*)&base[c8 * 8];
        *(uint4*)dst = v;
    }
    __syncthreads();

    const int q = t >> 3;
    const int s = t & 7;
    const int i = i0 + q;

    float qreg[64];
#pragma unroll
    for (int c = 0; c < 8; ++c) {
        uint4 u = *(const uint4*)&Qs[q][c * 8];
        qreg[c*8+0] = lo2f(u.x); qreg[c*8+1] = hi2f(u.x);
        qreg[c*8+2] = lo2f(u.y); qreg[c*8+3] = hi2f(u.y);
        qreg[c*8+4] = lo2f(u.z); qreg[c*8+5] = hi2f(u.z);
        qreg[c*8+6] = lo2f(u.w); qreg[c*8+7] = hi2f(u.w);
    }

    float sreg[20];
    float lmax = -1e30f;
#pragma unroll
    for (int m = 0; m < 20; ++m) {
        const int j = s + 8 * m;
        const int g = i0 - HALF + j;
        const bool valid = (j >= q) && (j <= q + 2 * HALF) && (g >= 0) && (g < Nseq);
        float dot = 0.f;
#pragma unroll
        for (int c = 0; c < 8; ++c) {
            uint4 u = *(const uint4*)&Ks[j][c * 8];
            dot += qreg[c*8+0]*lo2f(u.x) + qreg[c*8+1]*hi2f(u.x)
                 + qreg[c*8+2]*lo2f(u.y) + qreg[c*8+3]*hi2f(u.y)
                 + qreg[c*8+4]*lo2f(u.z) + qreg[c*8+5]*hi2f(u.z)
                 + qreg[c*8+6]*lo2f(u.w) + qreg[c*8+7]*hi2f(u.w);
        }
        sreg[m] = valid ? dot * SCALEF : -1e30f;
        lmax = fmaxf(lmax, sreg[m]);
    }
    lmax = fmaxf(lmax, __shfl_xor(lmax, 1));
    lmax = fmaxf(lmax, __shfl_xor(lmax, 2));
    lmax = fmaxf(lmax, __shfl_xor(lmax, 4));

    float lsum = 0.f;
#pragma unroll
    for (int m = 0; m < 20; ++m) {
        const float p = (sreg[m] > -1e29f) ? __expf(sreg[m] - lmax) : 0.f;
        lsum += p;
        sc[q][s + 8 * m] = f2bf(p);
    }
    lsum += __shfl_xor(lsum, 1);
    lsum += __shfl_xor(lsum, 2);
    lsum += __shfl_xor(lsum, 4);
    const float inv = 1.f / lsum;

    __syncthreads();

    const int d0 = s * 8;
    float acc[8] = {};
    for (int m0 = 0; m0 < 20; ++m0) {
        const int jb = m0 * 8;
        if (jb + 7 < q || jb > q + 2 * HALF) continue;
        uint4 up = *(const uint4*)&sc[q][jb];
        const float pv[8] = {lo2f(up.x), hi2f(up.x), lo2f(up.y), hi2f(up.y),
                             lo2f(up.z), hi2f(up.z), lo2f(up.w), hi2f(up.w)};
#pragma unroll
        for (int jj = 0; jj < 8; ++jj) {
            uint4 uv = *(const uint4*)&Vs[jb + jj][d0];
            const float p = pv[jj];
            acc[0] += p * lo2f(uv.x); acc[1] += p * hi2f(uv.x);
            acc[2] += p * lo2f(uv.y); acc[3] += p * hi2f(uv.y);
            acc[4] += p * lo2f(uv.z); acc[5] += p * hi2f(uv.z);
            acc[6] += p * lo2f(uv.w); acc[7] += p * hi2f(uv.w);
        }
    }

    unsigned short* orow = &ab[((size_t)(b * Nseq + i)) * Cdim + hoff + d0];
    union { unsigned short us[8]; uint4 u; } pk;
#pragma unroll
    for (int d = 0; d < 8; ++d) pk.us[d] = f2bf(acc[d] * inv);
    *(uint4*)orow = pk.u;
}

// ---------------------------------------------------------------------------
extern "C" void kernel_launch(void* const* d_in, const int* in_sizes, int n_in,
                              void* d_out, int out_size, void* d_ws, size_t ws_size,
                              hipStream_t stream)
{
    const float* x      = (const float*)d_in[0];
    const float* w_qkv  = (const float*)d_in[1];
    const float* w_proj = (const float*)d_in[2];
    const float* b_proj = (const float*)d_in[3];
    float* out = (float*)d_out;

    // ws (bf16 shorts): xb 3,145,728 | wb 1,769,472 | wpb 589,824 |
    // qkvb 4096*2304 = 9,437,184 | ab 3,145,728   -> 36.2 MB total
    unsigned short* xb   = (unsigned short*)d_ws;
    unsigned short* wb   = xb   + 3145728;
    unsigned short* wpb  = wb   + 1769472;
    unsigned short* qkvb = wpb  + 589824;
    unsigned short* ab   = qkvb + 9437184;

    f32_to_bf16<<<3145728 / 1024, 256, 0, stream>>>(x, xb, 3145728);
    f32_to_bf16<<<1769472 / 1024, 256, 0, stream>>>(w_qkv, wb, 1769472);
    f32_to_bf16<<< 589824 / 1024, 256, 0, stream>>>(w_proj, wpb, 589824);

    qkv_mfma<<<dim3(E3 / 128, (Bsz * Nseq) / 128), 256, 0, stream>>>(
        xb, wb, qkvb);

    swin_attn<<<dim3(Nseq / TQ, Bsz * Hh), 256, 0, stream>>>(qkvb, ab);

    proj_mfma<<<dim3(Cdim / 128, (Bsz * Nseq) / 128), 256, 0, stream>>>(
        ab, wpb, b_proj, out);
}

// Round 12
// 252.804 us; speedup vs baseline: 1.0893x; 1.0893x over previous
//
#include <hip/hip_runtime.h>
#include <hip/hip_bf16.h>

// Attention_82841329205539: B=2, N=2048, C=768, H=12, D=64, window=129
// Inputs fp32 (dict order), OUTPUT fp32 [B,N,C].
// r6:1485 r7:809 r8:444 r10:270 r11:275 us.
// r11 lesson: qkv is latency/occupancy-bound (2.25 blk/CU, barrier-drained
// loads), NOT store-pattern-bound. This round: fused converts, 128x64 tiles,
// reg-prefetch pipeline, XCD swizzle, leaner swin LDS.
#define Bsz   2
#define Nseq  2048
#define Cdim  768
#define E3    2304
#define Hh    12
#define Dd    64
#define HALF  64
#define SCALEF 0.125f

typedef __attribute__((ext_vector_type(8))) short short8;
typedef __attribute__((ext_vector_type(4))) float f32x4;

__device__ __forceinline__ unsigned short f2bf(float f) {
    unsigned int u = __float_as_uint(f);
    u = (u + 0x7FFFu + ((u >> 16) & 1u)) >> 16;
    return (unsigned short)u;
}
__device__ __forceinline__ float lo2f(unsigned int u) { return __uint_as_float(u << 16); }
__device__ __forceinline__ float hi2f(unsigned int u) { return __uint_as_float(u & 0xffff0000u); }
// packed fp32x2 -> bf16x2 (RNE, v_cvt_pk_bf16_f32)
__device__ __forceinline__ unsigned int pk2(float a, float b) {
    __hip_bfloat162 h = __float22bfloat162_rn(make_float2(a, b));
    union { __hip_bfloat162 h2; unsigned int u; } cv; cv.h2 = h; return cv.u;
}

// ---------------------------------------------------------------------------
// MFMA GEMM, tile 128M x 64N, BK=64, 256 thr = 4 waves (wm=M-half, wn=N-half
// of 32 cols). Wave: 4x2 mfma 16x16x32 bf16. fp32 inputs converted inline.
// Frag layouts (m89/m91): A/B elem j = M[row=lane&15][k=quad*8+j];
// C/D: m=quad*4+reg, n=lane&15.
// ---------------------------------------------------------------------------
#define AST 72   // LDS row stride (shorts), 144 B = 16B-aligned, bank-spread

// Kernel 1: QKV projection (fp32 x,w) -> bf16 qkv[bn][2304] row-major.
// grid (36, 32) XCD-swizzled into 8 patches of 9 cols x 16 rows.
__global__ __launch_bounds__(256) void qkv_mfma(
    const float* __restrict__ x, const float* __restrict__ w,
    unsigned short* __restrict__ qkvb)
{
    __shared__ __align__(16) unsigned short smem[192 * AST];  // 27648 B
    unsigned short (*Al)[AST] = (unsigned short(*)[AST])smem;
    unsigned short (*Bl)[AST] = (unsigned short(*)[AST])(smem + 128 * AST);

    const int t  = threadIdx.x;
    const int id = blockIdx.y * 36 + blockIdx.x;
    const int p8 = id & 7, jb2 = id >> 3;
    const int bx = (p8 & 3) * 9 + (jb2 % 9);
    const int by = (p8 >> 2) * 16 + (jb2 / 9);
    const int row0 = by * 128, col0 = bx * 64;

    const int lane = t & 63, wave = t >> 6;
    const int wm = wave >> 1, wn = wave & 1;
    const int ln = lane & 15, quad = lane >> 4;

    const int rA = t >> 3, c8 = t & 7;           // A rows rA, rA+32.. ; chunk c8

    float4 a0[4], a1[4], b0[2], b1[2];
    f32x4 acc[4][2] = {};

    // prefetch k0 = 0
#pragma unroll
    for (int j = 0; j < 4; ++j) {
        const float* pa = &x[(size_t)(row0 + rA + j*32) * Cdim + c8*8];
        a0[j] = *(const float4*)pa; a1[j] = *(const float4*)(pa + 4);
    }
#pragma unroll
    for (int j = 0; j < 2; ++j) {
        const float* pb = &w[(size_t)(col0 + rA + j*32) * Cdim + c8*8];
        b0[j] = *(const float4*)pb; b1[j] = *(const float4*)(pb + 4);
    }

    for (int k0 = 0; k0 < Cdim; k0 += 64) {
        __syncthreads();
#pragma unroll
        for (int j = 0; j < 4; ++j)
            *(uint4*)&Al[rA + j*32][c8*8] = make_uint4(
                pk2(a0[j].x, a0[j].y), pk2(a0[j].z, a0[j].w),
                pk2(a1[j].x, a1[j].y), pk2(a1[j].z, a1[j].w));
#pragma unroll
        for (int j = 0; j < 2; ++j)
            *(uint4*)&Bl[rA + j*32][c8*8] = make_uint4(
                pk2(b0[j].x, b0[j].y), pk2(b0[j].z, b0[j].w),
                pk2(b1[j].x, b1[j].y), pk2(b1[j].z, b1[j].w));
        __syncthreads();
        if (k0 + 64 < Cdim) {   // prefetch next tile; latency hides under MFMA
            const int kn = k0 + 64;
#pragma unroll
            for (int j = 0; j < 4; ++j) {
                const float* pa = &x[(size_t)(row0 + rA + j*32) * Cdim + kn + c8*8];
                a0[j] = *(const float4*)pa; a1[j] = *(const float4*)(pa + 4);
            }
#pragma unroll
            for (int j = 0; j < 2; ++j) {
                const float* pb = &w[(size_t)(col0 + rA + j*32) * Cdim + kn + c8*8];
                b0[j] = *(const float4*)pb; b1[j] = *(const float4*)(pb + 4);
            }
        }
#pragma unroll
        for (int kk = 0; kk < 64; kk += 32) {
            short8 af[4], bf[2];
#pragma unroll
            for (int mi = 0; mi < 4; ++mi)
                af[mi] = *(const short8*)&Al[wm*64 + mi*16 + ln][kk + quad*8];
#pragma unroll
            for (int ni = 0; ni < 2; ++ni)
                bf[ni] = *(const short8*)&Bl[wn*32 + ni*16 + ln][kk + quad*8];
#pragma unroll
            for (int mi = 0; mi < 4; ++mi)
#pragma unroll
                for (int ni = 0; ni < 2; ++ni)
                    acc[mi][ni] = __builtin_amdgcn_mfma_f32_16x16x32_bf16(
                        af[mi], bf[ni], acc[mi][ni], 0, 0, 0);
        }
    }

    // epilogue: acc -> LDS bf16 tile -> coalesced uint4 stores
    __syncthreads();
    unsigned short (*Cs)[AST] = (unsigned short(*)[AST])smem;
#pragma unroll
    for (int mi = 0; mi < 4; ++mi)
#pragma unroll
        for (int ni = 0; ni < 2; ++ni)
#pragma unroll
            for (int reg = 0; reg < 4; ++reg)
                Cs[wm*64 + mi*16 + quad*4 + reg][wn*32 + ni*16 + ln] =
                    f2bf(acc[mi][ni][reg]);
    __syncthreads();
#pragma unroll
    for (int j = 0; j < 4; ++j)
        *(uint4*)&qkvb[(size_t)(row0 + rA + j*32) * E3 + col0 + c8*8] =
            *(const uint4*)&Cs[rA + j*32][c8*8];
}

// Kernel 3: output projection (bf16 ab x fp32 w_proj) + bias -> fp32 out.
// grid (12, 32) XCD-swizzled into 8 patches of 12 cols x 4 rows.
__global__ __launch_bounds__(256) void proj_mfma(
    const unsigned short* __restrict__ Ab, const float* __restrict__ w,
    const float* __restrict__ bias, float* __restrict__ out)
{
    __shared__ __align__(16) unsigned short smem[192 * AST];
    unsigned short (*Al)[AST] = (unsigned short(*)[AST])smem;
    unsigned short (*Bl)[AST] = (unsigned short(*)[AST])(smem + 128 * AST);

    const int t  = threadIdx.x;
    const int id = blockIdx.y * 12 + blockIdx.x;
    const int p8 = id & 7, jb2 = id >> 3;
    const int bx = jb2 % 12;
    const int by = p8 * 4 + jb2 / 12;
    const int row0 = by * 128, col0 = bx * 64;

    const int lane = t & 63, wave = t >> 6;
    const int wm = wave >> 1, wn = wave & 1;
    const int ln = lane & 15, quad = lane >> 4;
    const int rA = t >> 3, c8 = t & 7;

    uint4 aA[4]; float4 b0[2], b1[2];
    f32x4 acc[4][2] = {};

#pragma unroll
    for (int j = 0; j < 4; ++j)
        aA[j] = *(const uint4*)&Ab[(size_t)(row0 + rA + j*32) * Cdim + c8*8];
#pragma unroll
    for (int j = 0; j < 2; ++j) {
        const float* pb = &w[(size_t)(col0 + rA + j*32) * Cdim + c8*8];
        b0[j] = *(const float4*)pb; b1[j] = *(const float4*)(pb + 4);
    }

    for (int k0 = 0; k0 < Cdim; k0 += 64) {
        __syncthreads();
#pragma unroll
        for (int j = 0; j < 4; ++j)
            *(uint4*)&Al[rA + j*32][c8*8] = aA[j];
#pragma unroll
        for (int j = 0; j < 2; ++j)
            *(uint4*)&Bl[rA + j*32][c8*8] = make_uint4(
                pk2(b0[j].x, b0[j].y), pk2(b0[j].z, b0[j].w),
                pk2(b1[j].x, b1[j].y), pk2(b1[j].z, b1[j].w));
        __syncthreads();
        if (k0 + 64 < Cdim) {
            const int kn = k0 + 64;
#pragma unroll
            for (int j = 0; j < 4; ++j)
                aA[j] = *(const uint4*)&Ab[(size_t)(row0 + rA + j*32) * Cdim + kn + c8*8];
#pragma unroll
            for (int j = 0; j < 2; ++j) {
                const float* pb = &w[(size_t)(col0 + rA + j*32) * Cdim + kn + c8*8];
                b0[j] = *(const float4*)pb; b1[j] = *(const float4*)(pb + 4);
            }
        }
#pragma unroll
        for (int kk = 0; kk < 64; kk += 32) {
            short8 af[4], bf[2];
#pragma unroll
            for (int mi = 0; mi < 4; ++mi)
                af[mi] = *(const short8*)&Al[wm*64 + mi*16 + ln][kk + quad*8];
#pragma unroll
            for (int ni = 0; ni < 2; ++ni)
                bf[ni] = *(const short8*)&Bl[wn*32 + ni*16 + ln][kk + quad*8];
#pragma unroll
            for (int mi = 0; mi < 4; ++mi)
#pragma unroll
                for (int ni = 0; ni < 2; ++ni)
                    acc[mi][ni] = __builtin_amdgcn_mfma_f32_16x16x32_bf16(
                        af[mi], bf[ni], acc[mi][ni], 0, 0, 0);
        }
    }

    // epilogue: two 32-col fp32 passes through LDS, fused bias
    float (*Csf)[36] = (float(*)[36])smem;    // 128 x 36 fp32 = 18432 B
#pragma unroll
    for (int p = 0; p < 2; ++p) {
        __syncthreads();
        if (wn == p)
#pragma unroll
            for (int mi = 0; mi < 4; ++mi)
#pragma unroll
                for (int ni = 0; ni < 2; ++ni)
#pragma unroll
                    for (int reg = 0; reg < 4; ++reg)
                        Csf[wm*64 + mi*16 + quad*4 + reg][ni*16 + ln] =
                            acc[mi][ni][reg];
        __syncthreads();
#pragma unroll
        for (int j = 0; j < 4; ++j) {
            const int F = t + j * 256, r = F >> 3, c4 = F & 7;
            const int col = col0 + p * 32 + c4 * 4;
            float4 v  = *(const float4*)&Csf[r][c4 * 4];
            float4 bv = *(const float4*)&bias[col];
            *(float4*)&out[(size_t)(row0 + r) * Cdim + col] =
                make_float4(v.x + bv.x, v.y + bv.y, v.z + bv.z, v.w + bv.w);
        }
    }
}

// ---------------------------------------------------------------------------
// Kernel 2: sliding-window attention. 32 q/block, K/V window (160 rows) in
// LDS bf16 (46 KB -> 3 blocks/CU); Q from global; p in regs + __shfl.
// grid (64, 24), 256 thr (8 lanes per query).
// ---------------------------------------------------------------------------
#define TQ   32
#define ROWS 160
#define KST  72

__global__ __launch_bounds__(256) void swin_attn(
    const unsigned short* __restrict__ qkvb, unsigned short* __restrict__ ab)
{
    __shared__ __align__(16) unsigned short Ks[ROWS][KST];   // 23040 B
    __shared__ __align__(16) unsigned short Vs[ROWS][KST];   // 23040 B

    const int t  = threadIdx.x;
    const int bh = blockIdx.y;
    const int b  = bh / Hh, h = bh % Hh;
    const int i0 = blockIdx.x * TQ;
    const int hoff = h * Dd;

    // stage K(160) + V(160) head-rows; OOB -> 0
    for (int F = t; F < 320 * 8; F += 256) {
        const int r = F >> 3, c8v = F & 7;
        const unsigned short* base = nullptr;
        unsigned short* dst;
        if (r < 160) {
            const int g = i0 - HALF + r;
            if (g >= 0 && g < Nseq)
                base = qkvb + (size_t)(b * Nseq + g) * E3 + Cdim + hoff;
            dst = &Ks[r][c8v * 8];
        } else {
            const int g = i0 - HALF + (r - 160);
            if (g >= 0 && g < Nseq)
                base = qkvb + (size_t)(b * Nseq + g) * E3 + 2 * Cdim + hoff;
            dst = &Vs[r - 160][c8v * 8];
        }
        uint4 v = make_uint4(0u, 0u, 0u, 0u);
        if (base) v = *(const uint4*)&base[c8v * 8];
        *(uint4*)dst = v;
    }

    const int q = t >> 3;
    const int s = t & 7;
    const int i = i0 + q;

    // Q row from global (8 lanes share the 128-B line; L1-served)
    float qreg[64];
    const unsigned short* qrow = qkvb + (size_t)(b * Nseq + i) * E3 + hoff;
#pragma unroll
    for (int c = 0; c < 8; ++c) {
        uint4 u = *(const uint4*)&qrow[c * 8];
        qreg[c*8+0] = lo2f(u.x); qreg[c*8+1] = hi2f(u.x);
        qreg[c*8+2] = lo2f(u.y); qreg[c*8+3] = hi2f(u.y);
        qreg[c*8+4] = lo2f(u.z); qreg[c*8+5] = hi2f(u.z);
        qreg[c*8+6] = lo2f(u.w); qreg[c*8+7] = hi2f(u.w);
    }
    __syncthreads();

    // scores: lane covers j = s + 8m
    float sreg[20];
    float lmax = -1e30f;
#pragma unroll
    for (int m = 0; m < 20; ++m) {
        const int j = s + 8 * m;
        const int g = i0 - HALF + j;
        const bool valid = (j >= q) && (j <= q + 2 * HALF) && (g >= 0) && (g < Nseq);
        float dot = 0.f;
#pragma unroll
        for (int c = 0; c < 8; ++c) {
            uint4 u = *(const uint4*)&Ks[j][c * 8];
            dot += qreg[c*8+0]*lo2f(u.x) + qreg[c*8+1]*hi2f(u.x)
                 + qreg[c*8+2]*lo2f(u.y) + qreg[c*8+3]*hi2f(u.y)
                 + qreg[c*8+4]*lo2f(u.z) + qreg[c*8+5]*hi2f(u.z)
                 + qreg[c*8+6]*lo2f(u.w) + qreg[c*8+7]*hi2f(u.w);
        }
        sreg[m] = valid ? dot * SCALEF : -1e30f;
        lmax = fmaxf(lmax, sreg[m]);
    }
    lmax = fmaxf(lmax, __shfl_xor(lmax, 1));
    lmax = fmaxf(lmax, __shfl_xor(lmax, 2));
    lmax = fmaxf(lmax, __shfl_xor(lmax, 4));

    float lsum = 0.f;
#pragma unroll
    for (int m = 0; m < 20; ++m) {
        const float p = (sreg[m] > -1e29f) ? __expf(sreg[m] - lmax) : 0.f;
        sreg[m] = p;            // keep p in registers (fp32 — no sc round-trip)
        lsum += p;
    }
    lsum += __shfl_xor(lsum, 1);
    lsum += __shfl_xor(lsum, 2);
    lsum += __shfl_xor(lsum, 4);
    const float inv = 1.f / lsum;

    // PV: lane owns d0..d0+7; p broadcast within the 8-lane team via shfl
    const int d0 = s * 8;
    const int tb = (t & 63) & 56;    // team base lane within wave
    float acc[8] = {};
#pragma unroll
    for (int m0 = 0; m0 < 20; ++m0) {
        const int jb = m0 * 8;
#pragma unroll
        for (int jj = 0; jj < 8; ++jj) {
            const float p = __shfl(sreg[m0], tb + jj);
            uint4 uv = *(const uint4*)&Vs[jb + jj][d0];
            acc[0] += p * lo2f(uv.x); acc[1] += p * hi2f(uv.x);
            acc[2] += p * lo2f(uv.y); acc[3] += p * hi2f(uv.y);
            acc[4] += p * lo2f(uv.z); acc[5] += p * hi2f(uv.z);
            acc[6] += p * lo2f(uv.w); acc[7] += p * hi2f(uv.w);
        }
    }

    unsigned short* orow = &ab[((size_t)(b * Nseq + i)) * Cdim + hoff + d0];
    union { unsigned short us[8]; uint4 u; } pk;
#pragma unroll
    for (int d = 0; d < 8; ++d) pk.us[d] = f2bf(acc[d] * inv);
    *(uint4*)orow = pk.u;
}

// ---------------------------------------------------------------------------
extern "C" void kernel_launch(void* const* d_in, const int* in_sizes, int n_in,
                              void* d_out, int out_size, void* d_ws, size_t ws_size,
                              hipStream_t stream)
{
    const float* x      = (const float*)d_in[0];
    const float* w_qkv  = (const float*)d_in[1];
    const float* w_proj = (const float*)d_in[2];
    const float* b_proj = (const float*)d_in[3];
    float* out = (float*)d_out;

    // ws (bf16): qkvb 9,437,184 | ab 3,145,728  -> 25.2 MB
    unsigned short* qkvb = (unsigned short*)d_ws;
    unsigned short* ab   = qkvb + 9437184;

    qkv_mfma<<<dim3(36, 32), 256, 0, stream>>>(x, w_qkv, qkvb);
    swin_attn<<<dim3(Nseq / TQ, Bsz * Hh), 256, 0, stream>>>(qkvb, ab);
    proj_mfma<<<dim3(12, 32), 256, 0, stream>>>(ab, w_proj, b_proj, out);
}

// Round 13
// 166.573 us; speedup vs baseline: 1.6532x; 1.5177x over previous
//
#include <hip/hip_runtime.h>
#include <hip/hip_bf16.h>

// Attention_82841329205539: B=2, N=2048, C=768, H=12, D=64, window=129
// Inputs fp32 (dict order), OUTPUT fp32 [B,N,C].
// r6:1485 r7:809 r8:444 r10:270 r11:275 r12:253 us.
// r12 lesson: swin was VALU-bound (scalar dot products). This round: MFMA
// flash-style swin (S=Q.K^T and O=Vt.P on the matrix pipe).
#define Bsz   2
#define Nseq  2048
#define Cdim  768
#define E3    2304
#define Hh    12
#define Dd    64
#define HALF  64
#define SCALEF 0.125f

typedef __attribute__((ext_vector_type(8))) short short8;
typedef __attribute__((ext_vector_type(4))) float f32x4;

__device__ __forceinline__ unsigned short f2bf(float f) {
    unsigned int u = __float_as_uint(f);
    u = (u + 0x7FFFu + ((u >> 16) & 1u)) >> 16;
    return (unsigned short)u;
}
__device__ __forceinline__ float lo2f(unsigned int u) { return __uint_as_float(u << 16); }
__device__ __forceinline__ float hi2f(unsigned int u) { return __uint_as_float(u & 0xffff0000u); }
__device__ __forceinline__ unsigned int pk2(float a, float b) {
    __hip_bfloat162 h = __float22bfloat162_rn(make_float2(a, b));
    union { __hip_bfloat162 h2; unsigned int u; } cv; cv.h2 = h; return cv.u;
}

#define AST 72

// ---------------------------------------------------------------------------
// Kernel 1: QKV projection (fp32 x,w) -> bf16 qkv[bn][2304] row-major.
// 128Mx64N tile, reg-prefetch pipeline, XCD swizzle. (unchanged from r12)
// ---------------------------------------------------------------------------
__global__ __launch_bounds__(256) void qkv_mfma(
    const float* __restrict__ x, const float* __restrict__ w,
    unsigned short* __restrict__ qkvb)
{
    __shared__ __align__(16) unsigned short smem[192 * AST];
    unsigned short (*Al)[AST] = (unsigned short(*)[AST])smem;
    unsigned short (*Bl)[AST] = (unsigned short(*)[AST])(smem + 128 * AST);

    const int t  = threadIdx.x;
    const int id = blockIdx.y * 36 + blockIdx.x;
    const int p8 = id & 7, jb2 = id >> 3;
    const int bx = (p8 & 3) * 9 + (jb2 % 9);
    const int by = (p8 >> 2) * 16 + (jb2 / 9);
    const int row0 = by * 128, col0 = bx * 64;

    const int lane = t & 63, wave = t >> 6;
    const int wm = wave >> 1, wn = wave & 1;
    const int ln = lane & 15, quad = lane >> 4;
    const int rA = t >> 3, c8 = t & 7;

    float4 a0[4], a1[4], b0[2], b1[2];
    f32x4 acc[4][2] = {};

#pragma unroll
    for (int j = 0; j < 4; ++j) {
        const float* pa = &x[(size_t)(row0 + rA + j*32) * Cdim + c8*8];
        a0[j] = *(const float4*)pa; a1[j] = *(const float4*)(pa + 4);
    }
#pragma unroll
    for (int j = 0; j < 2; ++j) {
        const float* pb = &w[(size_t)(col0 + rA + j*32) * Cdim + c8*8];
        b0[j] = *(const float4*)pb; b1[j] = *(const float4*)(pb + 4);
    }

    for (int k0 = 0; k0 < Cdim; k0 += 64) {
        __syncthreads();
#pragma unroll
        for (int j = 0; j < 4; ++j)
            *(uint4*)&Al[rA + j*32][c8*8] = make_uint4(
                pk2(a0[j].x, a0[j].y), pk2(a0[j].z, a0[j].w),
                pk2(a1[j].x, a1[j].y), pk2(a1[j].z, a1[j].w));
#pragma unroll
        for (int j = 0; j < 2; ++j)
            *(uint4*)&Bl[rA + j*32][c8*8] = make_uint4(
                pk2(b0[j].x, b0[j].y), pk2(b0[j].z, b0[j].w),
                pk2(b1[j].x, b1[j].y), pk2(b1[j].z, b1[j].w));
        __syncthreads();
        if (k0 + 64 < Cdim) {
            const int kn = k0 + 64;
#pragma unroll
            for (int j = 0; j < 4; ++j) {
                const float* pa = &x[(size_t)(row0 + rA + j*32) * Cdim + kn + c8*8];
                a0[j] = *(const float4*)pa; a1[j] = *(const float4*)(pa + 4);
            }
#pragma unroll
            for (int j = 0; j < 2; ++j) {
                const float* pb = &w[(size_t)(col0 + rA + j*32) * Cdim + kn + c8*8];
                b0[j] = *(const float4*)pb; b1[j] = *(const float4*)(pb + 4);
            }
        }
#pragma unroll
        for (int kk = 0; kk < 64; kk += 32) {
            short8 af[4], bf[2];
#pragma unroll
            for (int mi = 0; mi < 4; ++mi)
                af[mi] = *(const short8*)&Al[wm*64 + mi*16 + ln][kk + quad*8];
#pragma unroll
            for (int ni = 0; ni < 2; ++ni)
                bf[ni] = *(const short8*)&Bl[wn*32 + ni*16 + ln][kk + quad*8];
#pragma unroll
            for (int mi = 0; mi < 4; ++mi)
#pragma unroll
                for (int ni = 0; ni < 2; ++ni)
                    acc[mi][ni] = __builtin_amdgcn_mfma_f32_16x16x32_bf16(
                        af[mi], bf[ni], acc[mi][ni], 0, 0, 0);
        }
    }

    __syncthreads();
    unsigned short (*Cs)[AST] = (unsigned short(*)[AST])smem;
#pragma unroll
    for (int mi = 0; mi < 4; ++mi)
#pragma unroll
        for (int ni = 0; ni < 2; ++ni)
#pragma unroll
            for (int reg = 0; reg < 4; ++reg)
                Cs[wm*64 + mi*16 + quad*4 + reg][wn*32 + ni*16 + ln] =
                    f2bf(acc[mi][ni][reg]);
    __syncthreads();
#pragma unroll
    for (int j = 0; j < 4; ++j)
        *(uint4*)&qkvb[(size_t)(row0 + rA + j*32) * E3 + col0 + c8*8] =
            *(const uint4*)&Cs[rA + j*32][c8*8];
}

// ---------------------------------------------------------------------------
// Kernel 3: output projection + bias -> fp32 out. (unchanged from r12)
// ---------------------------------------------------------------------------
__global__ __launch_bounds__(256) void proj_mfma(
    const unsigned short* __restrict__ Ab, const float* __restrict__ w,
    const float* __restrict__ bias, float* __restrict__ out)
{
    __shared__ __align__(16) unsigned short smem[192 * AST];
    unsigned short (*Al)[AST] = (unsigned short(*)[AST])smem;
    unsigned short (*Bl)[AST] = (unsigned short(*)[AST])(smem + 128 * AST);

    const int t  = threadIdx.x;
    const int id = blockIdx.y * 12 + blockIdx.x;
    const int p8 = id & 7, jb2 = id >> 3;
    const int bx = jb2 % 12;
    const int by = p8 * 4 + jb2 / 12;
    const int row0 = by * 128, col0 = bx * 64;

    const int lane = t & 63, wave = t >> 6;
    const int wm = wave >> 1, wn = wave & 1;
    const int ln = lane & 15, quad = lane >> 4;
    const int rA = t >> 3, c8 = t & 7;

    uint4 aA[4]; float4 b0[2], b1[2];
    f32x4 acc[4][2] = {};

#pragma unroll
    for (int j = 0; j < 4; ++j)
        aA[j] = *(const uint4*)&Ab[(size_t)(row0 + rA + j*32) * Cdim + c8*8];
#pragma unroll
    for (int j = 0; j < 2; ++j) {
        const float* pb = &w[(size_t)(col0 + rA + j*32) * Cdim + c8*8];
        b0[j] = *(const float4*)pb; b1[j] = *(const float4*)(pb + 4);
    }

    for (int k0 = 0; k0 < Cdim; k0 += 64) {
        __syncthreads();
#pragma unroll
        for (int j = 0; j < 4; ++j)
            *(uint4*)&Al[rA + j*32][c8*8] = aA[j];
#pragma unroll
        for (int j = 0; j < 2; ++j)
            *(uint4*)&Bl[rA + j*32][c8*8] = make_uint4(
                pk2(b0[j].x, b0[j].y), pk2(b0[j].z, b0[j].w),
                pk2(b1[j].x, b1[j].y), pk2(b1[j].z, b1[j].w));
        __syncthreads();
        if (k0 + 64 < Cdim) {
            const int kn = k0 + 64;
#pragma unroll
            for (int j = 0; j < 4; ++j)
                aA[j] = *(const uint4*)&Ab[(size_t)(row0 + rA + j*32) * Cdim + kn + c8*8];
#pragma unroll
            for (int j = 0; j < 2; ++j) {
                const float* pb = &w[(size_t)(col0 + rA + j*32) * Cdim + kn + c8*8];
                b0[j] = *(const float4*)pb; b1[j] = *(const float4*)(pb + 4);
            }
        }
#pragma unroll
        for (int kk = 0; kk < 64; kk += 32) {
            short8 af[4], bf[2];
#pragma unroll
            for (int mi = 0; mi < 4; ++mi)
                af[mi] = *(const short8*)&Al[wm*64 + mi*16 + ln][kk + quad*8];
#pragma unroll
            for (int ni = 0; ni < 2; ++ni)
                bf[ni] = *(const short8*)&Bl[wn*32 + ni*16 + ln][kk + quad*8];
#pragma unroll
            for (int mi = 0; mi < 4; ++mi)
#pragma unroll
                for (int ni = 0; ni < 2; ++ni)
                    acc[mi][ni] = __builtin_amdgcn_mfma_f32_16x16x32_bf16(
                        af[mi], bf[ni], acc[mi][ni], 0, 0, 0);
        }
    }

    float (*Csf)[36] = (float(*)[36])smem;
#pragma unroll
    for (int p = 0; p < 2; ++p) {
        __syncthreads();
        if (wn == p)
#pragma unroll
            for (int mi = 0; mi < 4; ++mi)
#pragma unroll
                for (int ni = 0; ni < 2; ++ni)
#pragma unroll
                    for (int reg = 0; reg < 4; ++reg)
                        Csf[wm*64 + mi*16 + quad*4 + reg][ni*16 + ln] =
                            acc[mi][ni][reg];
        __syncthreads();
#pragma unroll
        for (int j = 0; j < 4; ++j) {
            const int F = t + j * 256, r = F >> 3, c4 = F & 7;
            const int col = col0 + p * 32 + c4 * 4;
            float4 v  = *(const float4*)&Csf[r][c4 * 4];
            float4 bv = *(const float4*)&bias[col];
            *(float4*)&out[(size_t)(row0 + r) * Cdim + col] =
                make_float4(v.x + bv.x, v.y + bv.y, v.z + bv.z, v.w + bv.w);
        }
    }
}

// ---------------------------------------------------------------------------
// Kernel 2: MFMA sliding-window attention. Block = 32 queries of one (b,h).
// S = Q.K^T via mfma (2 M-tiles x 10 N-tiles, K=64); softmax with shfl row-
// reduce + LDS combine; P -> LDS bf16; O = Vt.Pl via mfma (4 dim-tiles x
// 2 query-tiles, K=160). grid (64, 24), 256 thr = 4 waves. LDS 60.9 KB.
// ---------------------------------------------------------------------------
#define TQ   32
#define ROWS 160
#define KST  72     // Q/K row stride (shorts)
#define VST  168    // Vt/Pl row stride (shorts)

__global__ __launch_bounds__(256) void swin_attn(
    const unsigned short* __restrict__ qkvb, unsigned short* __restrict__ ab)
{
    __shared__ __align__(16) unsigned short Qs[TQ][KST];     //  4608 B
    __shared__ __align__(16) unsigned short Ks[ROWS][KST];   // 23040 B
    __shared__ __align__(16) unsigned short Vt[Dd][VST];     // 21504 B
    __shared__ __align__(16) unsigned short Pl[TQ][VST];     // 10752 B
    __shared__ float pmax[4][TQ];                            //   512 B
    __shared__ float psum[4][TQ];                            //   512 B

    const int t  = threadIdx.x;
    const int bh = blockIdx.y;
    const int b  = bh / Hh, h = bh % Hh;
    const int i0 = blockIdx.x * TQ;
    const int hoff = h * Dd;

    const int lane = t & 63, wave = t >> 6;
    const int ln = lane & 15, quad = lane >> 4;

    // ---- stage Q (32 rows) + K (160 rows) row-major
    for (int F = t; F < 192 * 8; F += 256) {
        const int r = F >> 3, c8 = F & 7;
        const unsigned short* base = nullptr;
        unsigned short* dst;
        if (r < 32) {
            base = qkvb + (size_t)(b * Nseq + (i0 + r)) * E3 + hoff;
            dst = &Qs[r][c8 * 8];
        } else {
            const int g = i0 - HALF + (r - 32);
            if (g >= 0 && g < Nseq)
                base = qkvb + (size_t)(b * Nseq + g) * E3 + Cdim + hoff;
            dst = &Ks[r - 32][c8 * 8];
        }
        uint4 v = make_uint4(0u, 0u, 0u, 0u);
        if (base) v = *(const uint4*)&base[c8 * 8];
        *(uint4*)dst = v;
    }
    // ---- stage V transposed: Vt[dim][key]
    for (int F = t; F < 160 * 8; F += 256) {
        const int r = F >> 3, c8 = F & 7;    // key row r, dim chunk c8
        const int g = i0 - HALF + r;
        uint4 v = make_uint4(0u, 0u, 0u, 0u);
        if (g >= 0 && g < Nseq)
            v = *(const uint4*)&qkvb[(size_t)(b * Nseq + g) * E3 + 2*Cdim + hoff + c8*8];
        union { unsigned short us[8]; uint4 u; } pk; pk.u = v;
#pragma unroll
        for (int jj = 0; jj < 8; ++jj)
            Vt[c8 * 8 + jj][r] = pk.us[jj];
    }
    __syncthreads();

    // ---- S phase: wave w -> mi = w&1 (query half), khalf = w>>1 (key half)
    const int mi    = wave & 1;
    const int khalf = wave >> 1;

    f32x4 sacc[5] = {};
#pragma unroll
    for (int kc = 0; kc < 2; ++kc) {            // K=64 in 2 chunks of 32
        short8 qf = *(const short8*)&Qs[mi*16 + ln][kc*32 + quad*8];
#pragma unroll
        for (int tt = 0; tt < 5; ++tt) {
            short8 kf = *(const short8*)&Ks[(khalf*5 + tt)*16 + ln][kc*32 + quad*8];
            sacc[tt] = __builtin_amdgcn_mfma_f32_16x16x32_bf16(qf, kf, sacc[tt], 0, 0, 0);
        }
    }

    // mask + scale; row max partials
    float p[5][4];
    float pm[4] = {-1e30f, -1e30f, -1e30f, -1e30f};
#pragma unroll
    for (int tt = 0; tt < 5; ++tt) {
        const int j = (khalf*5 + tt)*16 + ln;   // key idx in window
        const int g = i0 - HALF + j;
#pragma unroll
        for (int reg = 0; reg < 4; ++reg) {
            const int q = mi*16 + quad*4 + reg;
            const bool valid = (j >= q) && (j <= q + 2*HALF) && (g >= 0) && (g < Nseq);
            const float s = valid ? sacc[tt][reg] * SCALEF : -1e30f;
            p[tt][reg] = s;
            pm[reg] = fmaxf(pm[reg], s);
        }
    }
#pragma unroll
    for (int reg = 0; reg < 4; ++reg) {
        pm[reg] = fmaxf(pm[reg], __shfl_xor(pm[reg], 1));
        pm[reg] = fmaxf(pm[reg], __shfl_xor(pm[reg], 2));
        pm[reg] = fmaxf(pm[reg], __shfl_xor(pm[reg], 4));
        pm[reg] = fmaxf(pm[reg], __shfl_xor(pm[reg], 8));
    }
    if (ln == 0)
#pragma unroll
        for (int reg = 0; reg < 4; ++reg)
            pmax[wave][mi*16 + quad*4 + reg] = pm[reg];
    __syncthreads();

    // combined max; exp; row-sum partials; write P
    float ps[4] = {};
#pragma unroll
    for (int reg = 0; reg < 4; ++reg) {
        const int q = mi*16 + quad*4 + reg;
        const float cm = fmaxf(pmax[mi][q], pmax[mi | 2][q]);
#pragma unroll
        for (int tt = 0; tt < 5; ++tt) {
            const float pv = (p[tt][reg] > -1e29f) ? __expf(p[tt][reg] - cm) : 0.f;
            p[tt][reg] = pv;
            ps[reg] += pv;
        }
    }
#pragma unroll
    for (int reg = 0; reg < 4; ++reg) {
        ps[reg] += __shfl_xor(ps[reg], 1);
        ps[reg] += __shfl_xor(ps[reg], 2);
        ps[reg] += __shfl_xor(ps[reg], 4);
        ps[reg] += __shfl_xor(ps[reg], 8);
    }
    if (ln == 0)
#pragma unroll
        for (int reg = 0; reg < 4; ++reg)
            psum[wave][mi*16 + quad*4 + reg] = ps[reg];
#pragma unroll
    for (int tt = 0; tt < 5; ++tt)
#pragma unroll
        for (int reg = 0; reg < 4; ++reg)
            Pl[mi*16 + quad*4 + reg][(khalf*5 + tt)*16 + ln] = f2bf(p[tt][reg]);
    __syncthreads();

    // ---- PV phase: D[m=dim][n=query] = sum_key Vt[dim][key] * Pl[query][key]
    const int niq = wave & 1;              // query half
    const int mb  = (wave >> 1) * 2;       // dim-tile base
    f32x4 oacc[2] = {};
#pragma unroll
    for (int kc = 0; kc < 5; ++kc) {       // K=160 in 5 chunks of 32
        short8 pf = *(const short8*)&Pl[niq*16 + ln][kc*32 + quad*8];
#pragma unroll
        for (int m2 = 0; m2 < 2; ++m2) {
            short8 vf = *(const short8*)&Vt[(mb + m2)*16 + ln][kc*32 + quad*8];
            oacc[m2] = __builtin_amdgcn_mfma_f32_16x16x32_bf16(vf, pf, oacc[m2], 0, 0, 0);
        }
    }

    // normalize + write: query q = niq*16+ln; dims = (mb+m2)*16 + quad*4 + reg
    const int q = niq*16 + ln;
    const float inv = 1.f / (psum[q >> 4][q] + psum[(q >> 4) | 2][q]);
    unsigned short* orow = &ab[(size_t)(b * Nseq + i0 + q) * Cdim + hoff];
#pragma unroll
    for (int m2 = 0; m2 < 2; ++m2) {
        const int d0 = (mb + m2)*16 + quad*4;
        union { unsigned short us[4]; uint2 u2; } pk;
#pragma unroll
        for (int reg = 0; reg < 4; ++reg)
            pk.us[reg] = f2bf(oacc[m2][reg] * inv);
        *(uint2*)&orow[d0] = pk.u2;
    }
}

// ---------------------------------------------------------------------------
extern "C" void kernel_launch(void* const* d_in, const int* in_sizes, int n_in,
                              void* d_out, int out_size, void* d_ws, size_t ws_size,
                              hipStream_t stream)
{
    const float* x      = (const float*)d_in[0];
    const float* w_qkv  = (const float*)d_in[1];
    const float* w_proj = (const float*)d_in[2];
    const float* b_proj = (const float*)d_in[3];
    float* out = (float*)d_out;

    unsigned short* qkvb = (unsigned short*)d_ws;   // 9,437,184 shorts
    unsigned short* ab   = qkvb + 9437184;          // 3,145,728 shorts

    qkv_mfma<<<dim3(36, 32), 256, 0, stream>>>(x, w_qkv, qkvb);
    swin_attn<<<dim3(Nseq / TQ, Bsz * Hh), 256, 0, stream>>>(qkvb, ab);
    proj_mfma<<<dim3(12, 32), 256, 0, stream>>>(ab, w_proj, b_proj, out);
}

// Round 14
// 160.345 us; speedup vs baseline: 1.7175x; 1.0388x over previous
//
#include <hip/hip_runtime.h>
#include <hip/hip_bf16.h>

// Attention_82841329205539: B=2, N=2048, C=768, H=12, D=64, window=129
// Inputs fp32 (dict order), OUTPUT fp32 [B,N,C].
// r6:1485 r7:809 r8:444 r10:270 r11:275 r12:253 r13:166.6 us.
// r13 lesson: ~45us of dur is the harness's 268MB d_ws poison fill (fixed
// cost). Kernels are latency-bound: swin 2 blk/CU (LDS), proj 1.5 blk/CU
// (grid). This round: swin Vt-overlay (34.8KB -> 4 blk/CU) + V-in-regs,
// proj 64x64 tiles (8 blk/CU), qkv cvt moved out of barrier region.
#define Bsz   2
#define Nseq  2048
#define Cdim  768
#define E3    2304
#define Hh    12
#define Dd    64
#define HALF  64
#define SCALEF 0.125f

typedef __attribute__((ext_vector_type(8))) short short8;
typedef __attribute__((ext_vector_type(4))) float f32x4;

__device__ __forceinline__ unsigned short f2bf(float f) {
    unsigned int u = __float_as_uint(f);
    u = (u + 0x7FFFu + ((u >> 16) & 1u)) >> 16;
    return (unsigned short)u;
}
__device__ __forceinline__ unsigned int pk2(float a, float b) {
    __hip_bfloat162 h = __float22bfloat162_rn(make_float2(a, b));
    union { __hip_bfloat162 h2; unsigned int u; } cv; cv.h2 = h; return cv.u;
}
__device__ __forceinline__ uint4 cvt8(const float4& lo, const float4& hi) {
    return make_uint4(pk2(lo.x, lo.y), pk2(lo.z, lo.w),
                      pk2(hi.x, hi.y), pk2(hi.z, hi.w));
}

#define AST 72

// ---------------------------------------------------------------------------
// Kernel 1: QKV projection (fp32 x,w) -> bf16 qkv[bn][2304] row-major.
// 128Mx64N, BK=64, reg-prefetch; cvt AFTER mfma (out of serial region).
// grid (36, 32) XCD-swizzled.
// ---------------------------------------------------------------------------
__global__ __launch_bounds__(256) void qkv_mfma(
    const float* __restrict__ x, const float* __restrict__ w,
    unsigned short* __restrict__ qkvb)
{
    __shared__ __align__(16) unsigned short smem[192 * AST];
    unsigned short (*Al)[AST] = (unsigned short(*)[AST])smem;
    unsigned short (*Bl)[AST] = (unsigned short(*)[AST])(smem + 128 * AST);

    const int t  = threadIdx.x;
    const int id = blockIdx.y * 36 + blockIdx.x;
    const int p8 = id & 7, jb2 = id >> 3;
    const int bx = (p8 & 3) * 9 + (jb2 % 9);
    const int by = (p8 >> 2) * 16 + (jb2 / 9);
    const int row0 = by * 128, col0 = bx * 64;

    const int lane = t & 63, wave = t >> 6;
    const int wm = wave >> 1, wn = wave & 1;
    const int ln = lane & 15, quad = lane >> 4;
    const int rA = t >> 3, c8 = t & 7;

    float4 a0[4], a1[4], b0[2], b1[2];
    uint4  aC[4], bC[2];
    f32x4 acc[4][2] = {};

#pragma unroll
    for (int j = 0; j < 4; ++j) {
        const float* pa = &x[(size_t)(row0 + rA + j*32) * Cdim + c8*8];
        a0[j] = *(const float4*)pa; a1[j] = *(const float4*)(pa + 4);
    }
#pragma unroll
    for (int j = 0; j < 2; ++j) {
        const float* pb = &w[(size_t)(col0 + rA + j*32) * Cdim + c8*8];
        b0[j] = *(const float4*)pb; b1[j] = *(const float4*)(pb + 4);
    }
#pragma unroll
    for (int j = 0; j < 4; ++j) aC[j] = cvt8(a0[j], a1[j]);
#pragma unroll
    for (int j = 0; j < 2; ++j) bC[j] = cvt8(b0[j], b1[j]);

    for (int k0 = 0; k0 < Cdim; k0 += 64) {
        __syncthreads();
#pragma unroll
        for (int j = 0; j < 4; ++j) *(uint4*)&Al[rA + j*32][c8*8] = aC[j];
#pragma unroll
        for (int j = 0; j < 2; ++j) *(uint4*)&Bl[rA + j*32][c8*8] = bC[j];
        __syncthreads();
        const bool more = (k0 + 64 < Cdim);
        if (more) {
            const int kn = k0 + 64;
#pragma unroll
            for (int j = 0; j < 4; ++j) {
                const float* pa = &x[(size_t)(row0 + rA + j*32) * Cdim + kn + c8*8];
                a0[j] = *(const float4*)pa; a1[j] = *(const float4*)(pa + 4);
            }
#pragma unroll
            for (int j = 0; j < 2; ++j) {
                const float* pb = &w[(size_t)(col0 + rA + j*32) * Cdim + kn + c8*8];
                b0[j] = *(const float4*)pb; b1[j] = *(const float4*)(pb + 4);
            }
        }
#pragma unroll
        for (int kk = 0; kk < 64; kk += 32) {
            short8 af[4], bf[2];
#pragma unroll
            for (int mi = 0; mi < 4; ++mi)
                af[mi] = *(const short8*)&Al[wm*64 + mi*16 + ln][kk + quad*8];
#pragma unroll
            for (int ni = 0; ni < 2; ++ni)
                bf[ni] = *(const short8*)&Bl[wn*32 + ni*16 + ln][kk + quad*8];
#pragma unroll
            for (int mi = 0; mi < 4; ++mi)
#pragma unroll
                for (int ni = 0; ni < 2; ++ni)
                    acc[mi][ni] = __builtin_amdgcn_mfma_f32_16x16x32_bf16(
                        af[mi], bf[ni], acc[mi][ni], 0, 0, 0);
        }
        if (more) {   // cvt after MFMA: vmcnt wait lands here, not before MFMA
#pragma unroll
            for (int j = 0; j < 4; ++j) aC[j] = cvt8(a0[j], a1[j]);
#pragma unroll
            for (int j = 0; j < 2; ++j) bC[j] = cvt8(b0[j], b1[j]);
        }
    }

    __syncthreads();
    unsigned short (*Cs)[AST] = (unsigned short(*)[AST])smem;
#pragma unroll
    for (int mi = 0; mi < 4; ++mi)
#pragma unroll
        for (int ni = 0; ni < 2; ++ni)
#pragma unroll
            for (int reg = 0; reg < 4; ++reg)
                Cs[wm*64 + mi*16 + quad*4 + reg][wn*32 + ni*16 + ln] =
                    f2bf(acc[mi][ni][reg]);
    __syncthreads();
#pragma unroll
    for (int j = 0; j < 4; ++j)
        *(uint4*)&qkvb[(size_t)(row0 + rA + j*32) * E3 + col0 + c8*8] =
            *(const uint4*)&Cs[rA + j*32][c8*8];
}

// ---------------------------------------------------------------------------
// Kernel 3: output projection + bias -> fp32 out. 64Mx64N tile, BK=64,
// grid (12, 64) = 768 blocks, LDS 18.4KB -> high occupancy.
// Wave w owns rows w*16..+15; acc over 4 n-tiles.
// ---------------------------------------------------------------------------
__global__ __launch_bounds__(256) void proj_mfma(
    const unsigned short* __restrict__ Ab, const float* __restrict__ w,
    const float* __restrict__ bias, float* __restrict__ out)
{
    __shared__ __align__(16) unsigned short smem[128 * AST];  // 18432 B
    unsigned short (*Al)[AST] = (unsigned short(*)[AST])smem;
    unsigned short (*Bl)[AST] = (unsigned short(*)[AST])(smem + 64 * AST);

    const int t  = threadIdx.x;
    const int id = blockIdx.y * 12 + blockIdx.x;
    const int p8 = id & 7, j2 = id >> 3;        // 96 per XCD patch
    const int bx = j2 % 12;
    const int by = p8 * 8 + j2 / 12;
    const int row0 = by * 64, col0 = bx * 64;

    const int lane = t & 63, wave = t >> 6;
    const int ln = lane & 15, quad = lane >> 4;
    const int rA = t >> 3, c8 = t & 7;          // 32 rows per 256-thr pass

    uint4 aA[2], bC[2];
    float4 b0[2], b1[2];
    f32x4 acc[4] = {};

#pragma unroll
    for (int j = 0; j < 2; ++j)
        aA[j] = *(const uint4*)&Ab[(size_t)(row0 + rA + j*32) * Cdim + c8*8];
#pragma unroll
    for (int j = 0; j < 2; ++j) {
        const float* pb = &w[(size_t)(col0 + rA + j*32) * Cdim + c8*8];
        b0[j] = *(const float4*)pb; b1[j] = *(const float4*)(pb + 4);
    }
#pragma unroll
    for (int j = 0; j < 2; ++j) bC[j] = cvt8(b0[j], b1[j]);

    for (int k0 = 0; k0 < Cdim; k0 += 64) {
        __syncthreads();
#pragma unroll
        for (int j = 0; j < 2; ++j) *(uint4*)&Al[rA + j*32][c8*8] = aA[j];
#pragma unroll
        for (int j = 0; j < 2; ++j) *(uint4*)&Bl[rA + j*32][c8*8] = bC[j];
        __syncthreads();
        const bool more = (k0 + 64 < Cdim);
        if (more) {
            const int kn = k0 + 64;
#pragma unroll
            for (int j = 0; j < 2; ++j)
                aA[j] = *(const uint4*)&Ab[(size_t)(row0 + rA + j*32) * Cdim + kn + c8*8];
#pragma unroll
            for (int j = 0; j < 2; ++j) {
                const float* pb = &w[(size_t)(col0 + rA + j*32) * Cdim + kn + c8*8];
                b0[j] = *(const float4*)pb; b1[j] = *(const float4*)(pb + 4);
            }
        }
#pragma unroll
        for (int kc = 0; kc < 2; ++kc) {
            short8 af = *(const short8*)&Al[wave*16 + ln][kc*32 + quad*8];
#pragma unroll
            for (int ni = 0; ni < 4; ++ni) {
                short8 bf = *(const short8*)&Bl[ni*16 + ln][kc*32 + quad*8];
                acc[ni] = __builtin_amdgcn_mfma_f32_16x16x32_bf16(af, bf, acc[ni], 0, 0, 0);
            }
        }
        if (more) {
#pragma unroll
            for (int j = 0; j < 2; ++j) bC[j] = cvt8(b0[j], b1[j]);
        }
    }

    // epilogue: two 32-col fp32 passes via LDS, fused bias
    float (*Csf)[36] = (float(*)[36])smem;   // 64 x 36 fp32 = 9216 B
#pragma unroll
    for (int p = 0; p < 2; ++p) {
        __syncthreads();
#pragma unroll
        for (int ni = 0; ni < 2; ++ni) {
            const int nn = p * 2 + ni;
#pragma unroll
            for (int reg = 0; reg < 4; ++reg)
                Csf[wave*16 + quad*4 + reg][ni*16 + ln] = acc[nn][reg];
        }
        __syncthreads();
#pragma unroll
        for (int j = 0; j < 2; ++j) {
            const int F = t + j * 256, r = F >> 3, c4 = F & 7;
            const int col = col0 + p * 32 + c4 * 4;
            float4 v  = *(const float4*)&Csf[r][c4 * 4];
            float4 bv = *(const float4*)&bias[col];
            *(float4*)&out[(size_t)(row0 + r) * Cdim + col] =
                make_float4(v.x + bv.x, v.y + bv.y, v.z + bv.z, v.w + bv.w);
        }
    }
}

// ---------------------------------------------------------------------------
// Kernel 2: MFMA sliding-window attention, Vt overlaid on Ks (LDS 34.8KB ->
// 4 blk/CU). V prefetched to registers; Q frags from global. 3 barriers.
// grid (64, 24), 256 thr.
// ---------------------------------------------------------------------------
#define TQ   32
#define ROWS 160
#define KST  72
#define VST  168

__global__ __launch_bounds__(256) void swin_attn(
    const unsigned short* __restrict__ qkvb, unsigned short* __restrict__ ab)
{
    __shared__ __align__(16) unsigned short SH[ROWS * KST];  // 23040 B (Ks/Vt)
    __shared__ __align__(16) unsigned short Pl[TQ][VST];     // 10752 B
    __shared__ float pmax[4][TQ];                            //   512 B
    __shared__ float psum[4][TQ];                            //   512 B
    unsigned short (*Ks)[KST] = (unsigned short(*)[KST])SH;
    unsigned short (*Vt)[VST] = (unsigned short(*)[VST])SH;  // overlay

    const int t  = threadIdx.x;
    const int bh = blockIdx.y;
    const int b  = bh / Hh, h = bh % Hh;
    const int i0 = blockIdx.x * TQ;
    const int hoff = h * Dd;

    const int lane = t & 63, wave = t >> 6;
    const int ln = lane & 15, quad = lane >> 4;
    const int mi    = wave & 1;     // query half (S phase)
    const int khalf = wave >> 1;    // key half (S phase)

    // ---- prefetch: Q frags (regs), V rows (regs); stage K -> LDS
    short8 qf[2];
#pragma unroll
    for (int kc = 0; kc < 2; ++kc)
        qf[kc] = *(const short8*)&qkvb[(size_t)(b * Nseq + i0 + mi*16 + ln) * E3
                                       + hoff + kc*32 + quad*8];
    uint4 vreg[5];
    const int rV = t >> 3, c8 = t & 7;
#pragma unroll
    for (int j = 0; j < 5; ++j) {
        const int r = rV + j * 32;            // key row 0..159
        const int g = i0 - HALF + r;
        uint4 v = make_uint4(0u, 0u, 0u, 0u);
        if (g >= 0 && g < Nseq)
            v = *(const uint4*)&qkvb[(size_t)(b * Nseq + g) * E3 + 2*Cdim + hoff + c8*8];
        vreg[j] = v;
    }
#pragma unroll
    for (int j = 0; j < 5; ++j) {
        const int r = rV + j * 32;
        const int g = i0 - HALF + r;
        uint4 v = make_uint4(0u, 0u, 0u, 0u);
        if (g >= 0 && g < Nseq)
            v = *(const uint4*)&qkvb[(size_t)(b * Nseq + g) * E3 + Cdim + hoff + c8*8];
        *(uint4*)&Ks[r][c8 * 8] = v;
    }
    __syncthreads();

    // ---- S phase
    f32x4 sacc[5] = {};
#pragma unroll
    for (int kc = 0; kc < 2; ++kc)
#pragma unroll
        for (int tt = 0; tt < 5; ++tt) {
            short8 kf = *(const short8*)&Ks[(khalf*5 + tt)*16 + ln][kc*32 + quad*8];
            sacc[tt] = __builtin_amdgcn_mfma_f32_16x16x32_bf16(qf[kc], kf, sacc[tt], 0, 0, 0);
        }

    float p[5][4];
    float pm[4] = {-1e30f, -1e30f, -1e30f, -1e30f};
#pragma unroll
    for (int tt = 0; tt < 5; ++tt) {
        const int j = (khalf*5 + tt)*16 + ln;
        const int g = i0 - HALF + j;
#pragma unroll
        for (int reg = 0; reg < 4; ++reg) {
            const int q = mi*16 + quad*4 + reg;
            const bool valid = (j >= q) && (j <= q + 2*HALF) && (g >= 0) && (g < Nseq);
            const float s = valid ? sacc[tt][reg] * SCALEF : -1e30f;
            p[tt][reg] = s;
            pm[reg] = fmaxf(pm[reg], s);
        }
    }
#pragma unroll
    for (int reg = 0; reg < 4; ++reg) {
        pm[reg] = fmaxf(pm[reg], __shfl_xor(pm[reg], 1));
        pm[reg] = fmaxf(pm[reg], __shfl_xor(pm[reg], 2));
        pm[reg] = fmaxf(pm[reg], __shfl_xor(pm[reg], 4));
        pm[reg] = fmaxf(pm[reg], __shfl_xor(pm[reg], 8));
    }
    if (ln == 0)
#pragma unroll
        for (int reg = 0; reg < 4; ++reg)
            pmax[wave][mi*16 + quad*4 + reg] = pm[reg];
    __syncthreads();   // pmax ready; all Ks reads complete (Vt overlay safe)

    // ---- exp, row sums, write P; overwrite Ks region with Vt
    float ps[4] = {};
#pragma unroll
    for (int reg = 0; reg < 4; ++reg) {
        const int q = mi*16 + quad*4 + reg;
        const float cm = fmaxf(pmax[mi][q], pmax[mi | 2][q]);
#pragma unroll
        for (int tt = 0; tt < 5; ++tt) {
            const float pv = (p[tt][reg] > -1e29f) ? __expf(p[tt][reg] - cm) : 0.f;
            p[tt][reg] = pv;
            ps[reg] += pv;
        }
    }
#pragma unroll
    for (int reg = 0; reg < 4; ++reg) {
        ps[reg] += __shfl_xor(ps[reg], 1);
        ps[reg] += __shfl_xor(ps[reg], 2);
        ps[reg] += __shfl_xor(ps[reg], 4);
        ps[reg] += __shfl_xor(ps[reg], 8);
    }
    if (ln == 0)
#pragma unroll
        for (int reg = 0; reg < 4; ++reg)
            psum[wave][mi*16 + quad*4 + reg] = ps[reg];
#pragma unroll
    for (int tt = 0; tt < 5; ++tt)
#pragma unroll
        for (int reg = 0; reg < 4; ++reg)
            Pl[mi*16 + quad*4 + reg][(khalf*5 + tt)*16 + ln] = f2bf(p[tt][reg]);
    // Vt[dim][key] from vreg (transpose scalar stores)
#pragma unroll
    for (int j = 0; j < 5; ++j) {
        const int r = rV + j * 32;
        union { unsigned short us[8]; uint4 u; } pk; pk.u = vreg[j];
#pragma unroll
        for (int jj = 0; jj < 8; ++jj)
            Vt[c8 * 8 + jj][r] = pk.us[jj];
    }
    __syncthreads();

    // ---- PV phase: D[m=dim][n=query] = Vt . Pl^T
    const int niq = wave & 1;
    const int mb  = (wave >> 1) * 2;
    f32x4 oacc[2] = {};
#pragma unroll
    for (int kc = 0; kc < 5; ++kc) {
        short8 pf = *(const short8*)&Pl[niq*16 + ln][kc*32 + quad*8];
#pragma unroll
        for (int m2 = 0; m2 < 2; ++m2) {
            short8 vf = *(const short8*)&Vt[(mb + m2)*16 + ln][kc*32 + quad*8];
            oacc[m2] = __builtin_amdgcn_mfma_f32_16x16x32_bf16(vf, pf, oacc[m2], 0, 0, 0);
        }
    }

    const int q = niq*16 + ln;
    const float inv = 1.f / (psum[q >> 4][q] + psum[(q >> 4) | 2][q]);
    unsigned short* orow = &ab[(size_t)(b * Nseq + i0 + q) * Cdim + hoff];
#pragma unroll
    for (int m2 = 0; m2 < 2; ++m2) {
        const int d0 = (mb + m2)*16 + quad*4;
        union { unsigned short us[4]; uint2 u2; } pk;
#pragma unroll
        for (int reg = 0; reg < 4; ++reg)
            pk.us[reg] = f2bf(oacc[m2][reg] * inv);
        *(uint2*)&orow[d0] = pk.u2;
    }
}

// ---------------------------------------------------------------------------
extern "C" void kernel_launch(void* const* d_in, const int* in_sizes, int n_in,
                              void* d_out, int out_size, void* d_ws, size_t ws_size,
                              hipStream_t stream)
{
    const float* x      = (const float*)d_in[0];
    const float* w_qkv  = (const float*)d_in[1];
    const float* w_proj = (const float*)d_in[2];
    const float* b_proj = (const float*)d_in[3];
    float* out = (float*)d_out;

    unsigned short* qkvb = (unsigned short*)d_ws;   // 9,437,184 shorts
    unsigned short* ab   = qkvb + 9437184;          // 3,145,728 shorts

    qkv_mfma<<<dim3(36, 32), 256, 0, stream>>>(x, w_qkv, qkvb);
    swin_attn<<<dim3(Nseq / TQ, Bsz * Hh), 256, 0, stream>>>(qkvb, ab);
    proj_mfma<<<dim3(12, 64), 256, 0, stream>>>(ab, w_proj, b_proj, out);
}